// Round 9
// baseline (1172.595 us; speedup 1.0000x reference)
//
#include <hip/hip_runtime.h>

// SSIM over (C=8, H=2048, W=2048) fp32, 11x11 separable Gaussian, zero pad.
// Row-streaming separable, 1 px/thread, macro-expanded phases (static acc
// indexing). Round-8: occupancy 2x (CHUNK 64 -> 2048 blocks = 8/CU) and
// (x,y)-interleaved f32x2 LDS row buffer (halves LDS instruction count).

typedef float f32x2 __attribute__((ext_vector_type(2)));

#define CHN 8
#define HIMG 2048
#define WIMG 2048
#define SW 256
#define CHUNK 64
#define NCHUNK 32           // 32*64 = 2048 exactly
#define ROWS (CHUNK + 10)   // 74 input rows streamed
#define NIT 7               // 7*11 = 77 >= 74
#define LC 268              // LDS cols: global c0-6 .. c0+261

#define C1F 1.0e-4f
#define C2F 9.0e-4f

__device__ __forceinline__ float rfl(float v) {
    return __int_as_float(__builtin_amdgcn_readfirstlane(__float_as_int(v)));
}

// One streamed row. PH = rpc % 11 (compile-time). Slot s=(PH+j)%11 gets
// vertical tap wc[10-j]; j==10 births the slot; slot PH finalizes.
#define PHASE(PHC)                                                          \
  {                                                                         \
    constexpr int PH = (PHC);                                               \
    const int rpc = it * 11 + PH;                                           \
    if (rpc < ROWS) {                                                       \
      f32x2* b = rowbuf[rpc & 1];                                           \
      b[6 + t] = (f32x2){cx, cy};                                           \
      if (isH) { b[hslot] = (f32x2){chx, chy}; }                            \
      float nx = 0.f, ny = 0.f, nhx = 0.f, nhy = 0.f;                       \
      {                                                                     \
        const int gr = R0 - 4 + rpc; /* next row's global index */          \
        if (rpc + 1 < ROWS && (unsigned)gr < (unsigned)HIMG) {              \
          const float* xr = xp + (size_t)gr * WIMG;                         \
          const float* yr = yp + (size_t)gr * WIMG;                         \
          nx = xr[gcm]; ny = yr[gcm];                                       \
          if (hok) { nhx = xr[gch]; nhy = yr[gch]; }                        \
        }                                                                   \
      }                                                                     \
      __syncthreads();                                                      \
      f32x2 hm = {0.f, 0.f}, hq = {0.f, 0.f};                               \
      float hxy = 0.f;                                                      \
      _Pragma("unroll")                                                     \
      for (int k = 0; k < 11; k++) {                                        \
        f32x2 v = b[t + 1 + k];                                             \
        f32x2 w2 = { wr[k], wr[k] };                                        \
        hm += w2 * v;                                                       \
        hq += w2 * (v * v);                                                 \
        hxy = fmaf(wr[k], v.x * v.y, hxy);                                  \
      }                                                                     \
      _Pragma("unroll")                                                     \
      for (int j = 0; j < 11; j++) {                                        \
        const int s = (PH + j) % 11;     /* constant after unroll */        \
        const float w = wc[10 - j];                                         \
        f32x2 w2 = { w, w };                                                \
        if (j == 10) {                                                      \
          accM[s] = w2 * hm;                                                \
          accQ[s] = w2 * hq;                                                \
          accXY[s] = w * hxy;                                               \
        } else {                                                            \
          accM[s] += w2 * hm;                                               \
          accQ[s] += w2 * hq;                                               \
          accXY[s] = fmaf(w, hxy, accXY[s]);                                \
        }                                                                   \
      }                                                                     \
      if (rpc >= 10) {                                                      \
        const float mx = accM[PH].x, my = accM[PH].y;                       \
        const float cxx = accQ[PH].x, cyy = accQ[PH].y;                     \
        const float cxy = accXY[PH];                                        \
        const float mx2 = mx * mx, my2 = my * my, mxy = mx * my;            \
        const float sx = cxx - mx2, sy = cyy - my2, sxy = cxy - mxy;        \
        const float num = fmaf(2.f, mxy, C1F) * fmaf(2.f, sxy, C2F);        \
        const float den = (mx2 + my2 + C1F) * (sx + sy + C2F);              \
        lsum += num * __builtin_amdgcn_rcpf(den);                           \
      }                                                                     \
      cx = nx; cy = ny; chx = nhx; chy = nhy;                               \
    }                                                                       \
  }

__global__ __launch_bounds__(256, 8)
void ssim_stream(const float* __restrict__ x, const float* __restrict__ y,
                 const float* __restrict__ kern, float* __restrict__ out)
{
    __shared__ __align__(16) f32x2 rowbuf[2][LC];   // (x,y) interleaved
    __shared__ float wavesum[4];

    const int t  = threadIdx.x;
    const int c0 = blockIdx.x * SW;
    const int R0 = blockIdx.y * CHUNK;
    const size_t chOff = (size_t)blockIdx.z * (size_t)(HIMG * WIMG);
    const float* xp = x + chOff;
    const float* yp = y + chOff;

    // separable 1-D weights (uniform)
    float wr[11], wc[11];
    {
        const float kc = rfl(kern[60]);
        #pragma unroll
        for (int k = 0; k < 11; k++) {
            wr[k] = rfl(kern[55 + k]);
            wc[k] = rfl(kern[k * 11 + 5]) / kc;
        }
    }

    // geometry: main col + (threads 0..11) halo col
    const int gcm = c0 + t;
    const bool isH = (t < 12);
    const int hslot = (t < 6) ? t : (256 + t);            // 0..5 | 262..267
    const int gch  = (t < 6) ? (c0 - 6 + t) : (c0 + 250 + t);
    const bool hok = isH && ((unsigned)gch < (unsigned)WIMG);

    // rotating vertical accumulators (static indexing only!)
    f32x2 accM[11];   // (mu_x, mu_y)
    f32x2 accQ[11];   // (E[xx], E[yy])
    float accXY[11];  // E[xy]
    #pragma unroll
    for (int s = 0; s < 11; s++) {
        accM[s] = {0.f, 0.f}; accQ[s] = {0.f, 0.f}; accXY[s] = 0.f;
    }

    float lsum = 0.f;
    float cx = 0.f, cy = 0.f, chx = 0.f, chy = 0.f;
    {
        const int gr = R0 - 5;                 // first streamed row
        if ((unsigned)gr < (unsigned)HIMG) {
            const float* xr = xp + (size_t)gr * WIMG;
            const float* yr = yp + (size_t)gr * WIMG;
            cx = xr[gcm]; cy = yr[gcm];
            if (hok) { chx = xr[gch]; chy = yr[gch]; }
        }
    }

    #pragma unroll 1
    for (int it = 0; it < NIT; it++) {
        PHASE(0) PHASE(1) PHASE(2) PHASE(3) PHASE(4) PHASE(5)
        PHASE(6) PHASE(7) PHASE(8) PHASE(9) PHASE(10)
    }

    // block reduction -> one atomic
    #pragma unroll
    for (int off = 32; off > 0; off >>= 1)
        lsum += __shfl_down(lsum, off, 64);
    if ((t & 63) == 0) wavesum[t >> 6] = lsum;
    __syncthreads();
    if (t == 0) {
        const float s = wavesum[0] + wavesum[1] + wavesum[2] + wavesum[3];
        atomicAdd(out, s * (1.0f / 33554432.0f));   // * 2^-25 (exact)
    }
}

extern "C" void kernel_launch(void* const* d_in, const int* in_sizes, int n_in,
                              void* d_out, int out_size, void* d_ws, size_t ws_size,
                              hipStream_t stream) {
    const float* x = (const float*)d_in[0];
    const float* y = (const float*)d_in[1];
    const float* k = (const float*)d_in[2];
    float* out = (float*)d_out;

    hipMemsetAsync(d_out, 0, sizeof(float), stream);
    dim3 grid(WIMG / SW, NCHUNK, CHN);   // 8 x 32 x 8 = 2048 blocks
    ssim_stream<<<grid, 256, 0, stream>>>(x, y, k, out);
}

// Round 11
// 337.786 us; speedup vs baseline: 3.4714x; 3.4714x over previous
//
#include <hip/hip_runtime.h>

// SSIM over (C=8, H=2048, W=2048) fp32, 11x11 separable Gaussian, zero pad.
// Row-streaming separable, 1 px/thread, macro-expanded phases (static acc
// indexing). Round-10: CHUNK=64 (2048 blocks) + f32x2-interleaved rowbuf
// kept from round 9, but launch bounds back to (256,4) — round 9's (256,8)
// forced VGPR 64->32 and re-introduced a 3.9 GB scratch spill.

typedef float f32x2 __attribute__((ext_vector_type(2)));

#define CHN 8
#define HIMG 2048
#define WIMG 2048
#define SW 256
#define CHUNK 64
#define NCHUNK 32           // 32*64 = 2048 exactly
#define ROWS (CHUNK + 10)   // 74 input rows streamed
#define NIT 7               // 7*11 = 77 >= 74
#define LC 268              // LDS cols: global c0-6 .. c0+261

#define C1F 1.0e-4f
#define C2F 9.0e-4f

__device__ __forceinline__ float rfl(float v) {
    return __int_as_float(__builtin_amdgcn_readfirstlane(__float_as_int(v)));
}

// One streamed row. PH = rpc % 11 (compile-time). Slot s=(PH+j)%11 gets
// vertical tap wc[10-j]; j==10 births the slot; slot PH finalizes.
#define PHASE(PHC)                                                          \
  {                                                                         \
    constexpr int PH = (PHC);                                               \
    const int rpc = it * 11 + PH;                                           \
    if (rpc < ROWS) {                                                       \
      f32x2* b = rowbuf[rpc & 1];                                           \
      b[6 + t] = (f32x2){cx, cy};                                           \
      if (isH) { b[hslot] = (f32x2){chx, chy}; }                            \
      float nx = 0.f, ny = 0.f, nhx = 0.f, nhy = 0.f;                       \
      {                                                                     \
        const int gr = R0 - 4 + rpc; /* next row's global index */          \
        if (rpc + 1 < ROWS && (unsigned)gr < (unsigned)HIMG) {              \
          const float* xr = xp + (size_t)gr * WIMG;                         \
          const float* yr = yp + (size_t)gr * WIMG;                         \
          nx = xr[gcm]; ny = yr[gcm];                                       \
          if (hok) { nhx = xr[gch]; nhy = yr[gch]; }                        \
        }                                                                   \
      }                                                                     \
      __syncthreads();                                                      \
      f32x2 hm = {0.f, 0.f}, hq = {0.f, 0.f};                               \
      float hxy = 0.f;                                                      \
      _Pragma("unroll")                                                     \
      for (int k = 0; k < 11; k++) {                                        \
        f32x2 v = b[t + 1 + k];                                             \
        f32x2 w2 = { wr[k], wr[k] };                                        \
        hm += w2 * v;                                                       \
        hq += w2 * (v * v);                                                 \
        hxy = fmaf(wr[k], v.x * v.y, hxy);                                  \
      }                                                                     \
      _Pragma("unroll")                                                     \
      for (int j = 0; j < 11; j++) {                                        \
        const int s = (PH + j) % 11;     /* constant after unroll */        \
        const float w = wc[10 - j];                                         \
        f32x2 w2 = { w, w };                                                \
        if (j == 10) {                                                      \
          accM[s] = w2 * hm;                                                \
          accQ[s] = w2 * hq;                                                \
          accXY[s] = w * hxy;                                               \
        } else {                                                            \
          accM[s] += w2 * hm;                                               \
          accQ[s] += w2 * hq;                                               \
          accXY[s] = fmaf(w, hxy, accXY[s]);                                \
        }                                                                   \
      }                                                                     \
      if (rpc >= 10) {                                                      \
        const float mx = accM[PH].x, my = accM[PH].y;                       \
        const float cxx = accQ[PH].x, cyy = accQ[PH].y;                     \
        const float cxy = accXY[PH];                                        \
        const float mx2 = mx * mx, my2 = my * my, mxy = mx * my;            \
        const float sx = cxx - mx2, sy = cyy - my2, sxy = cxy - mxy;        \
        const float num = fmaf(2.f, mxy, C1F) * fmaf(2.f, sxy, C2F);        \
        const float den = (mx2 + my2 + C1F) * (sx + sy + C2F);              \
        lsum += num * __builtin_amdgcn_rcpf(den);                           \
      }                                                                     \
      cx = nx; cy = ny; chx = nhx; chy = nhy;                               \
    }                                                                       \
  }

__global__ __launch_bounds__(256, 4)
void ssim_stream(const float* __restrict__ x, const float* __restrict__ y,
                 const float* __restrict__ kern, float* __restrict__ out)
{
    __shared__ __align__(16) f32x2 rowbuf[2][LC];   // (x,y) interleaved
    __shared__ float wavesum[4];

    const int t  = threadIdx.x;
    const int c0 = blockIdx.x * SW;
    const int R0 = blockIdx.y * CHUNK;
    const size_t chOff = (size_t)blockIdx.z * (size_t)(HIMG * WIMG);
    const float* xp = x + chOff;
    const float* yp = y + chOff;

    // separable 1-D weights (uniform)
    float wr[11], wc[11];
    {
        const float kc = rfl(kern[60]);
        #pragma unroll
        for (int k = 0; k < 11; k++) {
            wr[k] = rfl(kern[55 + k]);
            wc[k] = rfl(kern[k * 11 + 5]) / kc;
        }
    }

    // geometry: main col + (threads 0..11) halo col
    const int gcm = c0 + t;
    const bool isH = (t < 12);
    const int hslot = (t < 6) ? t : (256 + t);            // 0..5 | 262..267
    const int gch  = (t < 6) ? (c0 - 6 + t) : (c0 + 250 + t);
    const bool hok = isH && ((unsigned)gch < (unsigned)WIMG);

    // rotating vertical accumulators (static indexing only!)
    f32x2 accM[11];   // (mu_x, mu_y)
    f32x2 accQ[11];   // (E[xx], E[yy])
    float accXY[11];  // E[xy]
    #pragma unroll
    for (int s = 0; s < 11; s++) {
        accM[s] = {0.f, 0.f}; accQ[s] = {0.f, 0.f}; accXY[s] = 0.f;
    }

    float lsum = 0.f;
    float cx = 0.f, cy = 0.f, chx = 0.f, chy = 0.f;
    {
        const int gr = R0 - 5;                 // first streamed row
        if ((unsigned)gr < (unsigned)HIMG) {
            const float* xr = xp + (size_t)gr * WIMG;
            const float* yr = yp + (size_t)gr * WIMG;
            cx = xr[gcm]; cy = yr[gcm];
            if (hok) { chx = xr[gch]; chy = yr[gch]; }
        }
    }

    #pragma unroll 1
    for (int it = 0; it < NIT; it++) {
        PHASE(0) PHASE(1) PHASE(2) PHASE(3) PHASE(4) PHASE(5)
        PHASE(6) PHASE(7) PHASE(8) PHASE(9) PHASE(10)
    }

    // block reduction -> one atomic
    #pragma unroll
    for (int off = 32; off > 0; off >>= 1)
        lsum += __shfl_down(lsum, off, 64);
    if ((t & 63) == 0) wavesum[t >> 6] = lsum;
    __syncthreads();
    if (t == 0) {
        const float s = wavesum[0] + wavesum[1] + wavesum[2] + wavesum[3];
        atomicAdd(out, s * (1.0f / 33554432.0f));   // * 2^-25 (exact)
    }
}

extern "C" void kernel_launch(void* const* d_in, const int* in_sizes, int n_in,
                              void* d_out, int out_size, void* d_ws, size_t ws_size,
                              hipStream_t stream) {
    const float* x = (const float*)d_in[0];
    const float* y = (const float*)d_in[1];
    const float* k = (const float*)d_in[2];
    float* out = (float*)d_out;

    hipMemsetAsync(d_out, 0, sizeof(float), stream);
    dim3 grid(WIMG / SW, NCHUNK, CHN);   // 8 x 32 x 8 = 2048 blocks
    ssim_stream<<<grid, 256, 0, stream>>>(x, y, k, out);
}